// Round 1
// baseline (11456.364 us; speedup 1.0000x reference)
//
#include <hip/hip_runtime.h>
#include <cstdint>

#define NB 4   // batch

// ======================================================================
// Weight transpose for pcw: w[512][23040] -> wt[23040][512]
// (23040 = 2560*9, row index = c*9 + (ky*3+kx))
// ======================================================================
__global__ void wtrans_k(const float* __restrict__ w, float* __restrict__ wt) {
  __shared__ float t[32][33];
  int bx = blockIdx.x;                 // 720 tiles over 23040
  int by = blockIdx.y;                 // 16 tiles over 512
  int x = threadIdx.x & 31, yq = threadIdx.x >> 5;   // 32 x 8
#pragma unroll
  for (int k = 0; k < 4; ++k) {
    int co = by * 32 + yq + k * 8;
    t[yq + k * 8][x] = w[(long)co * 23040 + bx * 32 + x];
  }
  __syncthreads();
#pragma unroll
  for (int k = 0; k < 4; ++k) {
    int row = bx * 32 + yq + k * 8;    // c9 index
    wt[(long)row * 512 + by * 32 + x] = t[x][yq + k * 8];
  }
}

// ======================================================================
// conv3x3 pad=1 on 16x16 planes (w5): in [B,Cin,16,16] -> out [B,Cout,16,16]
// bn (scale,bias) + relu fused. grid (Cout/4, B), block 256 (= 16x16 px)
// ======================================================================
__global__ __launch_bounds__(256) void conv3x3_s16(
    const float* __restrict__ in, const float* __restrict__ w,
    const float* __restrict__ bnS, const float* __restrict__ bnB,
    float* __restrict__ out, int Cin, int Cout) {
  const int co0 = blockIdx.x * 4;
  const int n = blockIdx.y;
  const int tid = threadIdx.x;
  const int px = tid & 15, py = tid >> 4;
  __shared__ float lin[8][18][18];
  float acc[4] = {0.f, 0.f, 0.f, 0.f};
  for (int c0 = 0; c0 < Cin; c0 += 8) {
    __syncthreads();
    for (int i = tid; i < 8 * 324; i += 256) {
      int ck = i / 324, r = i - ck * 324;
      int y = r / 18, x = r - y * 18;
      int gy = y - 1, gx = x - 1;
      float v = 0.f;
      if ((unsigned)gy < 16u && (unsigned)gx < 16u)
        v = in[(((long)n * Cin + c0 + ck) * 16 + gy) * 16 + gx];
      (&lin[0][0][0])[i] = v;
    }
    __syncthreads();
#pragma unroll
    for (int ck = 0; ck < 8; ++ck) {
#pragma unroll
      for (int ky = 0; ky < 3; ++ky) {
#pragma unroll
        for (int kx = 0; kx < 3; ++kx) {
          float iv = lin[ck][py + ky][px + kx];
#pragma unroll
          for (int o = 0; o < 4; ++o)
            acc[o] = fmaf(iv, w[(((long)(co0 + o) * Cin + c0 + ck) * 3 + ky) * 3 + kx], acc[o]);
        }
      }
    }
  }
#pragma unroll
  for (int o = 0; o < 4; ++o) {
    float v = fmaxf(fmaf(acc[o], bnS[co0 + o], bnB[co0 + o]), 0.f);
    out[(((long)n * Cout + co0 + o) * 16 + py) * 16 + px] = v;
  }
}

// ======================================================================
// Tiled 1x1 conv (+bn, optional relu), optional bilinear-resized input.
// tile: 64 cout x 64 pixels; CK=16; thread does 4co x 4px.
// grid (P/64, ceil(Cout/64), B), block 256.
// ======================================================================
template <int RESIZE>
__global__ __launch_bounds__(256) void conv1x1_tile(
    const float* __restrict__ in, const float* __restrict__ w,
    const float* __restrict__ bnS, const float* __restrict__ bnB,
    float* __restrict__ out, int Cin, int Cout,
    int Hi, int Wi, int Ho, int Wo, int relu) {
  const int P = Ho * Wo;
  const int n = blockIdx.z;
  const int co0 = blockIdx.y * 64;
  const int p0 = blockIdx.x * 64;
  const int tid = threadIdx.x;
  __shared__ float in_l[16][64];
  __shared__ float w_l[16][68];
  const int cosub = (tid & 15) * 4;
  const int psub = (tid >> 4) * 4;
  float acc[4][4] = {};
  float ry = 0.f, rx = 0.f;
  if (RESIZE) {
    ry = (float)((double)(Hi - 1) / (double)(Ho > 1 ? Ho - 1 : 1));
    rx = (float)((double)(Wi - 1) / (double)(Wo > 1 ? Wo - 1 : 1));
  }
  for (int c0 = 0; c0 < Cin; c0 += 16) {
    __syncthreads();
    {
      int i = tid;
#pragma unroll
      for (int it = 0; it < 4; ++it, i += 256) {   // input 16x64, p fastest
        int k = i >> 6, p = i & 63;
        int gp = p0 + p;
        float v = 0.f;
        if (gp < P) {
          if (RESIZE) {
            int oy = gp / Wo, ox = gp - (gp / Wo) * Wo;
            float ty = oy * ry, tx = ox * rx;
            int y0 = (int)ty, x0 = (int)tx;
            int y1 = min(y0 + 1, Hi - 1), x1 = min(x0 + 1, Wi - 1);
            float fy = ty - y0, fx = tx - x0;
            const float* base = in + (long)(n * Cin + c0 + k) * Hi * Wi;
            float v00 = base[y0 * Wi + x0], v01 = base[y0 * Wi + x1];
            float v10 = base[y1 * Wi + x0], v11 = base[y1 * Wi + x1];
            float a = v00 * (1.f - fy) + v10 * fy;    // y-lerp first (ref order)
            float b = v01 * (1.f - fy) + v11 * fy;
            v = a * (1.f - fx) + b * fx;
          } else {
            v = in[(long)(n * Cin + c0 + k) * P + gp];
          }
        }
        in_l[k][p] = v;
      }
      i = tid;
#pragma unroll
      for (int it = 0; it < 4; ++it, i += 256) {   // weights 16x64, k fastest
        int co = i >> 4, k = i & 15;
        float v = 0.f;
        if (co0 + co < Cout) v = w[(long)(co0 + co) * Cin + c0 + k];
        w_l[k][co] = v;
      }
    }
    __syncthreads();
#pragma unroll
    for (int k = 0; k < 16; ++k) {
      float a0 = in_l[k][psub + 0], a1 = in_l[k][psub + 1];
      float a2 = in_l[k][psub + 2], a3 = in_l[k][psub + 3];
      float b0 = w_l[k][cosub + 0], b1 = w_l[k][cosub + 1];
      float b2 = w_l[k][cosub + 2], b3 = w_l[k][cosub + 3];
      acc[0][0] = fmaf(b0, a0, acc[0][0]); acc[0][1] = fmaf(b0, a1, acc[0][1]);
      acc[0][2] = fmaf(b0, a2, acc[0][2]); acc[0][3] = fmaf(b0, a3, acc[0][3]);
      acc[1][0] = fmaf(b1, a0, acc[1][0]); acc[1][1] = fmaf(b1, a1, acc[1][1]);
      acc[1][2] = fmaf(b1, a2, acc[1][2]); acc[1][3] = fmaf(b1, a3, acc[1][3]);
      acc[2][0] = fmaf(b2, a0, acc[2][0]); acc[2][1] = fmaf(b2, a1, acc[2][1]);
      acc[2][2] = fmaf(b2, a2, acc[2][2]); acc[2][3] = fmaf(b2, a3, acc[2][3]);
      acc[3][0] = fmaf(b3, a0, acc[3][0]); acc[3][1] = fmaf(b3, a1, acc[3][1]);
      acc[3][2] = fmaf(b3, a2, acc[3][2]); acc[3][3] = fmaf(b3, a3, acc[3][3]);
    }
  }
#pragma unroll
  for (int o = 0; o < 4; ++o) {
    int co = co0 + cosub + o;
    if (co >= Cout) break;
    float sc = bnS ? bnS[co] : 1.f;
    float bb = bnB ? bnB[co] : 0.f;
#pragma unroll
    for (int pp = 0; pp < 4; ++pp) {
      int gp = p0 + psub + pp;
      if (gp < P) {
        float v = fmaf(acc[o][pp], sc, bb);
        if (relu) v = fmaxf(v, 0.f);
        out[(long)(n * Cout + co) * P + gp] = v;
      }
    }
  }
}

// ======================================================================
// attention scores + softmax over 9 dilated-3x3 neighbors (dilation 2, pad 2)
// q,k: [B,KD,H,W] -> att [B,H,W,9].  thread per pixel.
// ======================================================================
__global__ void att_scores(const float* __restrict__ q, const float* __restrict__ k,
                           float* __restrict__ att, int KD, int H, int W) {
  int n = blockIdx.y;
  int p = blockIdx.x * 256 + threadIdx.x;
  if (p >= H * W) return;
  int y = p / W, x = p - (p / W) * W;
  float sc[9] = {};
  const float* qb = q + (long)n * KD * H * W;
  const float* kb = k + (long)n * KD * H * W;
  for (int c = 0; c < KD; ++c) {
    float qv = qb[(long)c * H * W + p];
#pragma unroll
    for (int j = 0; j < 9; ++j) {
      int yy = y + (j / 3) * 2 - 2, xx = x + (j % 3) * 2 - 2;
      float kv = ((unsigned)yy < (unsigned)H && (unsigned)xx < (unsigned)W)
                     ? kb[(long)c * H * W + yy * W + xx] : 0.f;
      sc[j] = fmaf(qv, kv, sc[j]);
    }
  }
  float m = sc[0];
#pragma unroll
  for (int j = 1; j < 9; ++j) m = fmaxf(m, sc[j]);
  float e[9], ssum = 0.f;
#pragma unroll
  for (int j = 0; j < 9; ++j) { e[j] = expf(sc[j] - m); ssum += e[j]; }
  float inv = 1.f / ssum;
  float* ap = att + ((long)n * H * W + p) * 9;
#pragma unroll
  for (int j = 0; j < 9; ++j) ap[j] = e[j] * inv;
}

// ======================================================================
// PV: out[n,c,y,x] = sum_j att[n,y,x,j] * v[n,c,y+dy,x+dx]  (zero pad)
// grid (H * (W/xt), B) where xt=min(W,64); block 256 = (256/xt) cgroups x xt
// ======================================================================
__global__ void att_apply(const float* __restrict__ att, const float* __restrict__ v,
                          float* __restrict__ out, int C, int H, int W) {
  int n = blockIdx.y;
  int xt = (W < 64) ? W : 64;
  int wpb = W / xt;
  int y = blockIdx.x / wpb;
  int xb = (blockIdx.x - y * wpb) * xt;
  int lx = threadIdx.x % xt;
  int cg = threadIdx.x / xt;
  int ng = 256 / xt;
  int x = xb + lx;
  __shared__ float a_s[64][9];
  for (int i = threadIdx.x; i < xt * 9; i += 256)
    a_s[i / 9][i % 9] = att[(((long)n * H + y) * W + xb + i / 9) * 9 + (i % 9)];
  __syncthreads();
  float a[9];
#pragma unroll
  for (int j = 0; j < 9; ++j) a[j] = a_s[lx][j];
  for (int c = cg; c < C; c += ng) {
    const float* vb = v + ((long)n * C + c) * H * W;
    float acc = 0.f;
#pragma unroll
    for (int j = 0; j < 9; ++j) {
      int yy = y + (j / 3) * 2 - 2, xx = x + (j % 3) * 2 - 2;
      float vv = ((unsigned)yy < (unsigned)H && (unsigned)xx < (unsigned)W)
                     ? vb[yy * W + xx] : 0.f;
      acc = fmaf(a[j], vv, acc);
    }
    out[((long)n * C + c) * H * W + y * W + x] = acc;
  }
}

// ======================================================================
// bilinear resize align_corners=True (thread per output element)
// ======================================================================
__global__ void resize_k(const float* __restrict__ in, float* __restrict__ out,
                         int C, int Hi, int Wi, int Ho, int Wo, int Bn) {
  long total = (long)Bn * C * Ho * Wo;
  long idx = (long)blockIdx.x * 256 + threadIdx.x;
  if (idx >= total) return;
  int x = (int)(idx % Wo); long t1 = idx / Wo;
  int y = (int)(t1 % Ho); long nc = t1 / Ho;
  float ry = (float)((double)(Hi - 1) / (double)(Ho > 1 ? Ho - 1 : 1));
  float rx = (float)((double)(Wi - 1) / (double)(Wo > 1 ? Wo - 1 : 1));
  float ty = y * ry, tx = x * rx;
  int y0 = (int)ty, x0 = (int)tx;
  int y1 = min(y0 + 1, Hi - 1), x1 = min(x0 + 1, Wi - 1);
  float fy = ty - y0, fx = tx - x0;
  const float* b = in + nc * Hi * Wi;
  float v00 = b[y0 * Wi + x0], v01 = b[y0 * Wi + x1];
  float v10 = b[y1 * Wi + x0], v11 = b[y1 * Wi + x1];
  float a = v00 * (1.f - fy) + v10 * fy;
  float c = v01 * (1.f - fy) + v11 * fy;
  out[idx] = a * (1.f - fx) + c * fx;
}

// ======================================================================
// adaptive avg pool to s x s (torch bin boundaries). grid (s*s, B), block 256.
// ======================================================================
__global__ void apool_k(const float* __restrict__ in, float* __restrict__ out,
                        int C, int H, int W, int s) {
  int n = blockIdx.y, bin = blockIdx.x;
  int i = bin / s, j = bin - i * s;
  int h0 = (i * H) / s, h1 = ((i + 1) * H + s - 1) / s;
  int w0 = (j * W) / s, w1 = ((j + 1) * W + s - 1) / s;
  float inv = 1.f / (float)((h1 - h0) * (w1 - w0));
  for (int c = threadIdx.x; c < C; c += 256) {
    const float* b = in + ((long)n * C + c) * H * W;
    float acc = 0.f;
    for (int y = h0; y < h1; ++y)
      for (int x = w0; x < w1; ++x) acc += b[y * W + x];
    out[((long)n * C + c) * (s * s) + bin] = acc * inv;
  }
}

// ======================================================================
// tiny 1x1 conv for pooled features (P = s*s), bn+relu. grid (P, B), block 256.
// ======================================================================
__global__ void conv1x1_small(const float* __restrict__ in, const float* __restrict__ w,
                              const float* __restrict__ bnS, const float* __restrict__ bnB,
                              float* __restrict__ out, int Cin, int Cout, int P) {
  int n = blockIdx.y, p = blockIdx.x;
  __shared__ float vin[512];
  for (int i = threadIdx.x; i < Cin; i += 256)
    vin[i] = in[((long)n * Cin + i) * P + p];
  __syncthreads();
  for (int o = threadIdx.x; o < Cout; o += 256) {
    float acc = 0.f;
    const float* wr = w + (long)o * Cin;
    for (int c = 0; c < Cin; ++c) acc = fmaf(vin[c], wr[c], acc);
    out[((long)n * Cout + o) * P + p] = fmaxf(fmaf(acc, bnS[o], bnB[o]), 0.f);
  }
}

// ======================================================================
// THE BIG ONE: conv3x3 pad=1 over the virtual 2560-ch concat at 64x64.
// Channels 0-511 read from out3; 512+ are PPM features, bilinear-upsampled
// on the fly from pooled_post[s] (s in {1,2,3,6}). Weights pre-transposed
// to wt[c*9+t][512]. Tile: 64 cout x 16x16 px, CK=8, thread = 8co x 8px.
// grid (16, 8, B), block 256.
// ======================================================================
__global__ __launch_bounds__(256, 2) void conv3x3_psp(
    const float* __restrict__ out3,
    const float* __restrict__ pp1, const float* __restrict__ pp2,
    const float* __restrict__ pp3, const float* __restrict__ pp6,
    const float* __restrict__ wt, const float* __restrict__ bnS,
    const float* __restrict__ bnB, float* __restrict__ outp) {
  const int n = blockIdx.z;
  const int co0 = blockIdx.y * 64;
  const int y0 = (blockIdx.x >> 2) * 16, x0 = (blockIdx.x & 3) * 16;
  const int tid = threadIdx.x;
  __shared__ float in_l[8][18][18];
  __shared__ float w_l[8][9][64];
  const int cobase = (tid & 7) * 8;
  const int pg = tid >> 3;
  const int prow = pg >> 1;
  const int pxh = (pg & 1) * 8;
  float acc[8][8] = {};
  for (int c0 = 0; c0 < 2560; c0 += 8) {
    __syncthreads();
    // ---- stage weights: 8ck x 9tap x 64co (coalesced over co)
    for (int i = tid; i < 8 * 9 * 64; i += 256) {
      int co = i & 63, kk = i >> 6;
      int ck = kk / 9, t = kk - ck * 9;
      (&w_l[0][0][0])[i] = wt[((long)(c0 + ck)) * (9 * 512) + (long)t * 512 + co0 + co];
    }
    // ---- stage input 8 channels of 18x18 (halo), with PSP routing
    for (int i = tid; i < 8 * 324; i += 256) {
      int ck = i / 324, r = i - ck * 324;
      int yy = r / 18, xx = r - yy * 18;
      int gy = y0 + yy - 1, gx = x0 + xx - 1;
      float v = 0.f;
      if ((unsigned)gy < 64u && (unsigned)gx < 64u) {
        int c = c0 + ck;
        if (c < 512) {
          v = out3[(((long)n * 512 + c) * 64 + gy) * 64 + gx];
        } else {
          int grp = (c - 512) >> 9, lc = (c - 512) & 511;
          if (grp == 0) {
            v = pp1[(long)n * 512 + lc];
          } else {
            const float* pp; int s;
            if (grp == 1) { pp = pp2; s = 2; }
            else if (grp == 2) { pp = pp3; s = 3; }
            else { pp = pp6; s = 6; }
            float rr = (float)((double)(s - 1) / 63.0);
            float ty = gy * rr, tx = gx * rr;
            int iy0 = (int)ty, ix0 = (int)tx;
            int iy1 = min(iy0 + 1, s - 1), ix1 = min(ix0 + 1, s - 1);
            float fy = ty - iy0, fx = tx - ix0;
            const float* base = pp + ((long)n * 512 + lc) * s * s;
            float v00 = base[iy0 * s + ix0], v01 = base[iy0 * s + ix1];
            float v10 = base[iy1 * s + ix0], v11 = base[iy1 * s + ix1];
            float a = v00 * (1.f - fy) + v10 * fy;
            float b = v01 * (1.f - fy) + v11 * fy;
            v = a * (1.f - fx) + b * fx;
          }
        }
      }
      (&in_l[0][0][0])[i] = v;
    }
    __syncthreads();
#pragma unroll
    for (int ck = 0; ck < 8; ++ck) {
#pragma unroll
      for (int ky = 0; ky < 3; ++ky) {
        float rg[10];
        const float* rp = &in_l[ck][prow + ky][pxh];
#pragma unroll
        for (int q = 0; q < 10; ++q) rg[q] = rp[q];
#pragma unroll
        for (int kx = 0; kx < 3; ++kx) {
          float wv[8];
          const float* wp = &w_l[ck][ky * 3 + kx][cobase];
#pragma unroll
          for (int o = 0; o < 8; ++o) wv[o] = wp[o];
#pragma unroll
          for (int o = 0; o < 8; ++o)
#pragma unroll
            for (int p = 0; p < 8; ++p)
              acc[o][p] = fmaf(wv[o], rg[p + kx], acc[o][p]);
        }
      }
    }
  }
#pragma unroll
  for (int o = 0; o < 8; ++o) {
    int co = co0 + cobase + o;
    float sc = bnS[co], bb = bnB[co];
#pragma unroll
    for (int p = 0; p < 8; ++p) {
      float v = fmaxf(fmaf(acc[o][p], sc, bb), 0.f);
      outp[(((long)n * 512 + co) * 64 + (y0 + prow)) * 64 + (x0 + pxh + p)] = v;
    }
  }
}

// ======================================================================
extern "C" void kernel_launch(void* const* d_in, const int* in_sizes, int n_in,
                              void* d_out, int out_size, void* d_ws, size_t ws_size,
                              hipStream_t stream) {
  (void)in_sizes; (void)n_in; (void)out_size; (void)ws_size;
  // c1 (d_in[0]) is unused by the reference forward.
  const float* c2 = (const float*)d_in[1];
  const float* c3 = (const float*)d_in[2];
  const float* c4 = (const float*)d_in[3];
  const float* w5 = (const float*)d_in[4];
  const float* s5 = (const float*)d_in[5];
  const float* b5 = (const float*)d_in[6];
  const float* r4w = (const float*)d_in[7];
  const float* r4s = (const float*)d_in[8];
  const float* r4b = (const float*)d_in[9];
  const float* r4w2 = (const float*)d_in[10];
  const float* r4s2 = (const float*)d_in[11];
  const float* r4b2 = (const float*)d_in[12];
  const float* r3w = (const float*)d_in[13];
  const float* r3s = (const float*)d_in[14];
  const float* r3b = (const float*)d_in[15];
  const float* r3w2 = (const float*)d_in[16];
  const float* r3s2 = (const float*)d_in[17];
  const float* r3b2 = (const float*)d_in[18];
  const float* pw[4] = {(const float*)d_in[19], (const float*)d_in[22],
                        (const float*)d_in[25], (const float*)d_in[28]};
  const float* ps[4] = {(const float*)d_in[20], (const float*)d_in[23],
                        (const float*)d_in[26], (const float*)d_in[29]};
  const float* pbv[4] = {(const float*)d_in[21], (const float*)d_in[24],
                         (const float*)d_in[27], (const float*)d_in[30]};
  const float* pcw = (const float*)d_in[31];
  const float* pcs = (const float*)d_in[32];
  const float* pcb = (const float*)d_in[33];
  const float* w6 = (const float*)d_in[34];
  const float* b6 = (const float*)d_in[35];
  float* outp = (float*)d_out;

  char* ws = (char*)d_ws;
  size_t off = 0;
  auto alloc = [&](size_t bytes) -> float* {
    float* p = (float*)(ws + off);
    off += (bytes + 255) & ~(size_t)255;
    return p;
  };
  float* wt    = alloc(23040ULL * 512 * 4);            // 47.2 MB
  float* out5  = alloc((size_t)NB * 512 * 256 * 4);    // 2 MB
  float* out5r = alloc((size_t)NB * 512 * 1024 * 4);   // 8.4 MB
  float* q4    = alloc((size_t)NB * 128 * 1024 * 4);
  float* k4    = alloc((size_t)NB * 128 * 1024 * 4);
  float* att4  = alloc((size_t)NB * 1024 * 9 * 4);
  float* out4  = alloc((size_t)NB * 512 * 1024 * 4);
  float* out4r = alloc((size_t)NB * 512 * 4096 * 4);   // 33.6 MB
  float* q3    = alloc((size_t)NB * 64 * 4096 * 4);
  float* k3    = alloc((size_t)NB * 64 * 4096 * 4);
  float* att3  = alloc((size_t)NB * 4096 * 9 * 4);
  float* out3  = alloc((size_t)NB * 512 * 4096 * 4);   // 33.6 MB
  int ssv[4] = {1, 2, 3, 6};
  float* popre[4]; float* popost[4];
  for (int i = 0; i < 4; ++i) popre[i]  = alloc((size_t)NB * 512 * ssv[i] * ssv[i] * 4);
  for (int i = 0; i < 4; ++i) popost[i] = alloc((size_t)NB * 512 * ssv[i] * ssv[i] * 4);
  float* conv5 = alloc((size_t)NB * 512 * 4096 * 4);   // 33.6 MB  (total ~182 MB)

  // 0) transpose pcw weights
  wtrans_k<<<dim3(720, 16), 256, 0, stream>>>(pcw, wt);
  // 1) out5 = relu(bn(conv3x3(c4, w5)))            [B,512,16,16]
  conv3x3_s16<<<dim3(128, NB), 256, 0, stream>>>(c4, w5, s5, b5, out5, 2048, 512);
  // 2) level-4 local_up -> out4 [B,512,32,32]
  conv1x1_tile<0><<<dim3(16, 2, NB), 256, 0, stream>>>(c3, r4w, r4s, r4b, q4, 1024, 128, 32, 32, 32, 32, 0);
  conv1x1_tile<1><<<dim3(16, 2, NB), 256, 0, stream>>>(c4, r4w2, r4s2, r4b2, k4, 2048, 128, 16, 16, 32, 32, 0);
  att_scores<<<dim3(4, NB), 256, 0, stream>>>(q4, k4, att4, 128, 32, 32);
  resize_k<<<dim3(8192), 256, 0, stream>>>(out5, out5r, 512, 16, 16, 32, 32, NB);
  att_apply<<<dim3(32, NB), 256, 0, stream>>>(att4, out5r, out4, 512, 32, 32);
  // 3) level-3 local_up -> out3 [B,512,64,64]
  conv1x1_tile<0><<<dim3(64, 1, NB), 256, 0, stream>>>(c2, r3w, r3s, r3b, q3, 512, 64, 64, 64, 64, 64, 0);
  conv1x1_tile<1><<<dim3(64, 1, NB), 256, 0, stream>>>(c3, r3w2, r3s2, r3b2, k3, 1024, 64, 32, 32, 64, 64, 0);
  att_scores<<<dim3(16, NB), 256, 0, stream>>>(q3, k3, att3, 64, 64, 64);
  resize_k<<<dim3(32768), 256, 0, stream>>>(out4, out4r, 512, 32, 32, 64, 64, NB);
  att_apply<<<dim3(64, NB), 256, 0, stream>>>(att3, out4r, out3, 512, 64, 64);
  // 4) PPM pools + 1x1 convs (resize fused into the psp conv staging)
  for (int i = 0; i < 4; ++i) {
    apool_k<<<dim3(ssv[i] * ssv[i], NB), 256, 0, stream>>>(out3, popre[i], 512, 64, 64, ssv[i]);
    conv1x1_small<<<dim3(ssv[i] * ssv[i], NB), 256, 0, stream>>>(
        popre[i], pw[i], ps[i], pbv[i], popost[i], 512, 512, ssv[i] * ssv[i]);
  }
  // 5) big conv3x3 over virtual concat -> conv5 [B,512,64,64]
  conv3x3_psp<<<dim3(16, 8, NB), 256, 0, stream>>>(
      out3, popost[0], popost[1], popost[2], popost[3], wt, pcs, pcb, conv5);
  // 6) classifier 1x1 (bias only, no relu) -> d_out [B,19,64,64]
  conv1x1_tile<0><<<dim3(64, 1, NB), 256, 0, stream>>>(conv5, w6, nullptr, b6, outp, 512, 19, 64, 64, 64, 64, 0);
}

// Round 4
// 3481.579 us; speedup vs baseline: 3.2906x; 3.2906x over previous
//
#include <hip/hip_runtime.h>
#include <cstdint>

#define NB 4   // batch

typedef _Float16 f16x8 __attribute__((ext_vector_type(8)));
typedef float f32x16_t __attribute__((ext_vector_type(16)));

__device__ __forceinline__ void gload_lds16(const void* g, void* l) {
  // 16B direct global->LDS. LDS dest = wave-uniform base + lane*16 (linear).
  __builtin_amdgcn_global_load_lds((const __attribute__((address_space(1))) void*)g,
                                   (__attribute__((address_space(3))) void*)l, 16, 0, 0);
}

// ======================================================================
// Weight prep: wt16[co][t*Cc + c] = (f16) w[co][c*9 + t]
// grid (Cc/256, 9, 512)
// ======================================================================
__global__ void wprep_k(const float* __restrict__ w, _Float16* __restrict__ wt, int Cc) {
  int c = blockIdx.x * 256 + threadIdx.x;
  int t = blockIdx.y, co = blockIdx.z;
  wt[((size_t)co * 9 + t) * Cc + c] = (_Float16)w[((size_t)co * Cc + c) * 9 + t];
}

// ======================================================================
// NCHW fp32 -> NHWC f16.  grid (P/256, cslices, B)
// ======================================================================
__global__ void tonhwc_k(const float* __restrict__ in, _Float16* __restrict__ out,
                         int C, int P, int cs) {
  int n = blockIdx.z;
  int p = blockIdx.x * 256 + threadIdx.x;
  int c0 = blockIdx.y * cs;
  for (int c = c0; c < c0 + cs; ++c)
    out[((size_t)n * P + p) * C + c] = (_Float16)in[((size_t)n * C + c) * P + p];
}

// ======================================================================
// Implicit-GEMM conv3x3 (pad=1, dil=1) over a virtual channel-last f16 input
// split in two arrays: src0 for c<C0 (row stride C0), src1 for c>=C0 (row
// stride s1, channel index c-C0).  Weights wt[co][t*Cc+c] f16 (k contiguous).
// Out: fp32 NCHW [NB][512][H][W] with bn+relu.
// Block: 256 thr (4 waves), tile 128co x 128px, BK=64, 32x32x16 f16 MFMA.
// LDS frag-ordered: chunk ca=mf*4+kf (A), cb=nf*4+kf (B); [chunk][lane][16B].
// grid ((NB*H*W)/128, 4)
// ======================================================================
__global__ __launch_bounds__(256, 2) void gemm_conv3x3(
    const _Float16* __restrict__ wt,
    const _Float16* __restrict__ src0,
    const _Float16* __restrict__ src1,
    const _Float16* __restrict__ zbuf,
    const float* __restrict__ bnS, const float* __restrict__ bnB,
    float* __restrict__ outp,
    int Cc, int C0, int s1, int H, int W, int logW, int logHW, int relu)
{
  const int Ktot = 9 * Cc;
  const int tid = threadIdx.x;
  const int l = tid & 63, w = tid >> 6;
  const int wm = w >> 1, wn = w & 1;
  const int p0 = blockIdx.x * 128, co0 = blockIdx.y * 128;
  __shared__ __align__(16) _Float16 sm[32 * 512];   // A: 0..15, B: 16..31 (1KB chunks)

  const int ckoff = (l >> 5) * 8;      // per-lane k offset inside a chunk

  // A sources: chunk (mf=w, kf=i); k advances contiguously over the whole loop
  const _Float16* gA[4];
  {
    int co = co0 + w * 32 + (l & 31);
    const _Float16* base = wt + (size_t)co * Ktot + ckoff;
#pragma unroll
    for (int i = 0; i < 4; ++i) gA[i] = base + i * 16;
  }
  // B staging pixel (nf = w)
  const int pxs = p0 + w * 32 + (l & 31);
  const int xs = pxs & (W - 1), ys = (pxs >> logW) & (H - 1), ns = pxs >> logHW;

  f32x16_t acc00, acc01, acc10, acc11;
#pragma unroll
  for (int r = 0; r < 16; ++r) { acc00[r] = 0.f; acc01[r] = 0.f; acc10[r] = 0.f; acc11[r] = 0.f; }

  const int steps = Cc >> 6;
  for (int t = 0; t < 9; ++t) {
    // conv3x3 pad=1, DILATION=1: tap offsets -1/0/+1  (R3 bug: had *2-2)
    int gy = ys + (t / 3) - 1, gx = xs + (t % 3) - 1;
    bool ok = ((unsigned)gy < (unsigned)H) && ((unsigned)gx < (unsigned)W);
    size_t prow = ((size_t)ns << logHW) + (gy << logW) + gx;
    const _Float16* pb0 = ok ? src0 + prow * C0 + ckoff : zbuf + ckoff;
    const _Float16* pb1 = ok ? src1 + prow * s1 - C0 + ckoff : zbuf + ckoff;
    for (int s = 0; s < steps; ++s) {
      int cbase = s << 6;
      __syncthreads();               // previous compute finished with LDS
#pragma unroll
      for (int i = 0; i < 4; ++i) {  // A chunks (mf=w, kf=i)
        gload_lds16(gA[i], &sm[(w * 4 + i) * 512]);
        gA[i] += 64;
      }
#pragma unroll
      for (int i = 0; i < 4; ++i) {  // B chunks (nf=w, kf=i)
        int csel = cbase + i * 16;
        const _Float16* p = ((csel + ckoff) < C0 ? pb0 : pb1) + csel;
        gload_lds16(p, &sm[16 * 512 + (w * 4 + i) * 512]);
      }
      __syncthreads();               // compiler drains vmcnt before barrier
#pragma unroll
      for (int kf = 0; kf < 4; ++kf) {
        f16x8 a0 = *(const f16x8*)&sm[((wm * 2 + 0) * 4 + kf) * 512 + l * 8];
        f16x8 a1 = *(const f16x8*)&sm[((wm * 2 + 1) * 4 + kf) * 512 + l * 8];
        f16x8 b0 = *(const f16x8*)&sm[16 * 512 + ((wn * 2 + 0) * 4 + kf) * 512 + l * 8];
        f16x8 b1 = *(const f16x8*)&sm[16 * 512 + ((wn * 2 + 1) * 4 + kf) * 512 + l * 8];
        acc00 = __builtin_amdgcn_mfma_f32_32x32x16_f16(a0, b0, acc00, 0, 0, 0);
        acc01 = __builtin_amdgcn_mfma_f32_32x32x16_f16(a0, b1, acc01, 0, 0, 0);
        acc10 = __builtin_amdgcn_mfma_f32_32x32x16_f16(a1, b0, acc10, 0, 0, 0);
        acc11 = __builtin_amdgcn_mfma_f32_32x32x16_f16(a1, b1, acc11, 0, 0, 0);
      }
    }
  }

  // epilogue: D row = (r&3)+8*(r>>2)+4*(l>>5), col = l&31
  {
    const int xlo = l & 31;
#define EPI(ACC, ML, NL)                                                      \
    {                                                                         \
      int px = p0 + wn * 64 + (NL) * 32 + xlo;                                \
      int xx = px & (W - 1), yy = (px >> logW) & (H - 1), nn = px >> logHW;   \
      _Pragma("unroll")                                                       \
      for (int r = 0; r < 16; ++r) {                                          \
        int row = (r & 3) + 8 * (r >> 2) + 4 * (l >> 5);                      \
        int co = co0 + wm * 64 + (ML) * 32 + row;                             \
        float vv = fmaf(ACC[r], bnS[co], bnB[co]);                            \
        if (relu) vv = fmaxf(vv, 0.f);                                        \
        outp[(((size_t)nn * 512 + co) << logHW) + (yy << logW) + xx] = vv;    \
      }                                                                       \
    }
    EPI(acc00, 0, 0) EPI(acc01, 0, 1) EPI(acc10, 1, 0) EPI(acc11, 1, 1)
#undef EPI
  }
}

// ======================================================================
// Tiled 1x1 conv (+bn, optional relu), optional bilinear-resized input.
// tile: 64 cout x 64 pixels; CK=16; thread does 4co x 4px.
// grid (P/64, ceil(Cout/64), B), block 256.
// ======================================================================
template <int RESIZE>
__global__ __launch_bounds__(256) void conv1x1_tile(
    const float* __restrict__ in, const float* __restrict__ w,
    const float* __restrict__ bnS, const float* __restrict__ bnB,
    float* __restrict__ out, int Cin, int Cout,
    int Hi, int Wi, int Ho, int Wo, int relu) {
  const int P = Ho * Wo;
  const int n = blockIdx.z;
  const int co0 = blockIdx.y * 64;
  const int p0 = blockIdx.x * 64;
  const int tid = threadIdx.x;
  __shared__ float in_l[16][64];
  __shared__ float w_l[16][68];
  const int cosub = (tid & 15) * 4;
  const int psub = (tid >> 4) * 4;
  float acc[4][4] = {};
  float ry = 0.f, rx = 0.f;
  if (RESIZE) {
    ry = (float)((double)(Hi - 1) / (double)(Ho > 1 ? Ho - 1 : 1));
    rx = (float)((double)(Wi - 1) / (double)(Wo > 1 ? Wo - 1 : 1));
  }
  for (int c0 = 0; c0 < Cin; c0 += 16) {
    __syncthreads();
    {
      int i = tid;
#pragma unroll
      for (int it = 0; it < 4; ++it, i += 256) {
        int k = i >> 6, p = i & 63;
        int gp = p0 + p;
        float v = 0.f;
        if (gp < P) {
          if (RESIZE) {
            int oy = gp / Wo, ox = gp - (gp / Wo) * Wo;
            float ty = oy * ry, tx = ox * rx;
            int y0 = (int)ty, x0 = (int)tx;
            int y1 = min(y0 + 1, Hi - 1), x1 = min(x0 + 1, Wi - 1);
            float fy = ty - y0, fx = tx - x0;
            const float* base = in + (size_t)(n * Cin + c0 + k) * Hi * Wi;
            float v00 = base[y0 * Wi + x0], v01 = base[y0 * Wi + x1];
            float v10 = base[y1 * Wi + x0], v11 = base[y1 * Wi + x1];
            float a = v00 * (1.f - fy) + v10 * fy;
            float b = v01 * (1.f - fy) + v11 * fy;
            v = a * (1.f - fx) + b * fx;
          } else {
            v = in[(size_t)(n * Cin + c0 + k) * P + gp];
          }
        }
        in_l[k][p] = v;
      }
      i = tid;
#pragma unroll
      for (int it = 0; it < 4; ++it, i += 256) {
        int co = i >> 4, k = i & 15;
        float v = 0.f;
        if (co0 + co < Cout) v = w[(size_t)(co0 + co) * Cin + c0 + k];
        w_l[k][co] = v;
      }
    }
    __syncthreads();
#pragma unroll
    for (int k = 0; k < 16; ++k) {
      float a0 = in_l[k][psub + 0], a1 = in_l[k][psub + 1];
      float a2 = in_l[k][psub + 2], a3 = in_l[k][psub + 3];
      float b0 = w_l[k][cosub + 0], b1 = w_l[k][cosub + 1];
      float b2 = w_l[k][cosub + 2], b3 = w_l[k][cosub + 3];
      acc[0][0] = fmaf(b0, a0, acc[0][0]); acc[0][1] = fmaf(b0, a1, acc[0][1]);
      acc[0][2] = fmaf(b0, a2, acc[0][2]); acc[0][3] = fmaf(b0, a3, acc[0][3]);
      acc[1][0] = fmaf(b1, a0, acc[1][0]); acc[1][1] = fmaf(b1, a1, acc[1][1]);
      acc[1][2] = fmaf(b1, a2, acc[1][2]); acc[1][3] = fmaf(b1, a3, acc[1][3]);
      acc[2][0] = fmaf(b2, a0, acc[2][0]); acc[2][1] = fmaf(b2, a1, acc[2][1]);
      acc[2][2] = fmaf(b2, a2, acc[2][2]); acc[2][3] = fmaf(b2, a3, acc[2][3]);
      acc[3][0] = fmaf(b3, a0, acc[3][0]); acc[3][1] = fmaf(b3, a1, acc[3][1]);
      acc[3][2] = fmaf(b3, a2, acc[3][2]); acc[3][3] = fmaf(b3, a3, acc[3][3]);
    }
  }
#pragma unroll
  for (int o = 0; o < 4; ++o) {
    int co = co0 + cosub + o;
    if (co >= Cout) break;
    float sc = bnS ? bnS[co] : 1.f;
    float bb = bnB ? bnB[co] : 0.f;
#pragma unroll
    for (int pp = 0; pp < 4; ++pp) {
      int gp = p0 + psub + pp;
      if (gp < P) {
        float v = fmaf(acc[o][pp], sc, bb);
        if (relu) v = fmaxf(v, 0.f);
        out[(size_t)(n * Cout + co) * P + gp] = v;
      }
    }
  }
}

// ======================================================================
// attention scores + softmax over 9 dilated-3x3 neighbors (dilation 2, pad 2)
// q,k: [B,KD,H,W] -> att [B,H,W,9].  thread per pixel.
// ======================================================================
__global__ void att_scores(const float* __restrict__ q, const float* __restrict__ k,
                           float* __restrict__ att, int KD, int H, int W) {
  int n = blockIdx.y;
  int p = blockIdx.x * 256 + threadIdx.x;
  if (p >= H * W) return;
  int y = p / W, x = p - (p / W) * W;
  float sc[9] = {};
  const float* qb = q + (size_t)n * KD * H * W;
  const float* kb = k + (size_t)n * KD * H * W;
  for (int c = 0; c < KD; ++c) {
    float qv = qb[(size_t)c * H * W + p];
#pragma unroll
    for (int j = 0; j < 9; ++j) {
      int yy = y + (j / 3) * 2 - 2, xx = x + (j % 3) * 2 - 2;
      float kv = ((unsigned)yy < (unsigned)H && (unsigned)xx < (unsigned)W)
                     ? kb[(size_t)c * H * W + yy * W + xx] : 0.f;
      sc[j] = fmaf(qv, kv, sc[j]);
    }
  }
  float m = sc[0];
#pragma unroll
  for (int j = 1; j < 9; ++j) m = fmaxf(m, sc[j]);
  float e[9], ssum = 0.f;
#pragma unroll
  for (int j = 0; j < 9; ++j) { e[j] = expf(sc[j] - m); ssum += e[j]; }
  float inv = 1.f / ssum;
  float* ap = att + ((size_t)n * H * W + p) * 9;
#pragma unroll
  for (int j = 0; j < 9; ++j) ap[j] = e[j] * inv;
}

// ======================================================================
// PV with FUSED align-corners bilinear resize of v (Hv,Wv -> H,W).
// F16OUT=1: write channel-last f16 [n][H*W][C]; else fp32 NCHW.
// grid (H * (W/xt), B), block 256.
// ======================================================================
template <int F16OUT>
__global__ void att_apply_rs(const float* __restrict__ att, const float* __restrict__ v,
                             void* __restrict__ outp, int C, int H, int W, int Hv, int Wv) {
  int n = blockIdx.y;
  int xt = (W < 64) ? W : 64;
  int wpb = W / xt;
  int y = blockIdx.x / wpb;
  int xb = (blockIdx.x - y * wpb) * xt;
  int lx = threadIdx.x % xt, cg = threadIdx.x / xt, ng = 256 / xt;
  int x = xb + lx;
  __shared__ float a_s[64][9];
  for (int i = threadIdx.x; i < xt * 9; i += 256)
    a_s[i / 9][i % 9] = att[(((size_t)n * H + y) * W + xb + i / 9) * 9 + (i % 9)];
  __syncthreads();
  float a[9];
#pragma unroll
  for (int j = 0; j < 9; ++j) a[j] = a_s[lx][j];
  float rh = (float)(Hv - 1) / (float)(H - 1);
  float rw = (float)(Wv - 1) / (float)(W - 1);
  int o00[9], o01[9], o10[9], o11[9]; float w00[9], w01[9], w10[9], w11[9];
#pragma unroll
  for (int j = 0; j < 9; ++j) {
    int yy = y + (j / 3) * 2 - 2, xx = x + (j % 3) * 2 - 2;
    bool ok = ((unsigned)yy < (unsigned)H) && ((unsigned)xx < (unsigned)W);
    if (!ok) {
      o00[j] = o01[j] = o10[j] = o11[j] = 0;
      w00[j] = w01[j] = w10[j] = w11[j] = 0.f;
    } else {
      float ty = yy * rh, tx = xx * rw;
      int y0 = (int)ty, x0 = (int)tx;
      int y1 = min(y0 + 1, Hv - 1), x1 = min(x0 + 1, Wv - 1);
      float fy = ty - y0, fx = tx - x0;
      o00[j] = y0 * Wv + x0; o01[j] = y0 * Wv + x1;
      o10[j] = y1 * Wv + x0; o11[j] = y1 * Wv + x1;
      float aj = a[j];
      w00[j] = aj * (1.f - fy) * (1.f - fx); w01[j] = aj * (1.f - fy) * fx;
      w10[j] = aj * fy * (1.f - fx);         w11[j] = aj * fy * fx;
    }
  }
  for (int c = cg; c < C; c += ng) {
    const float* vb = v + ((size_t)n * C + c) * Hv * Wv;
    float acc = 0.f;
#pragma unroll
    for (int j = 0; j < 9; ++j)
      acc += w00[j] * vb[o00[j]] + w01[j] * vb[o01[j]] +
             w10[j] * vb[o10[j]] + w11[j] * vb[o11[j]];
    if (F16OUT)
      ((_Float16*)outp)[((size_t)n * H * W + (size_t)y * W + x) * C + c] = (_Float16)acc;
    else
      ((float*)outp)[((size_t)n * C + c) * (size_t)(H * W) + (size_t)y * W + x] = acc;
  }
}

// ======================================================================
// adaptive avg pool from channel-last f16 [n][4096][512] -> SUMS (atomic)
// grid (s*s, B, slices), block 256 (threads = channels c, c+256)
// ======================================================================
__global__ void apool_cl_k(const _Float16* __restrict__ in, float* __restrict__ out,
                           int s, int slices) {
  int bin = blockIdx.x, n = blockIdx.y, sl = blockIdx.z;
  int i = bin / s, j = bin - i * s;
  int h0 = (i * 64) / s, h1 = ((i + 1) * 64 + s - 1) / s;
  int w0 = (j * 64) / s, w1 = ((j + 1) * 64 + s - 1) / s;
  float a0 = 0.f, a1 = 0.f;
  for (int y = h0 + sl; y < h1; y += slices)
    for (int x = w0; x < w1; ++x) {
      const _Float16* r = in + ((size_t)n * 4096 + y * 64 + x) * 512;
      a0 += (float)r[threadIdx.x];
      a1 += (float)r[threadIdx.x + 256];
    }
  atomicAdd(&out[((size_t)n * 512 + threadIdx.x) * (s * s) + bin], a0);
  atomicAdd(&out[((size_t)n * 512 + threadIdx.x + 256) * (s * s) + bin], a1);
}

// ======================================================================
// tiny 1x1 conv for pooled SUMS (divides by bin area), bn+relu.
// grid (s*s, B), block 256.
// ======================================================================
__global__ void conv1x1_small(const float* __restrict__ in, const float* __restrict__ w,
                              const float* __restrict__ bnS, const float* __restrict__ bnB,
                              float* __restrict__ out, int Cin, int Cout, int s) {
  int n = blockIdx.y, p = blockIdx.x;
  int P = s * s;
  int bi = p / s, bj = p - bi * s;
  int h0 = (bi * 64) / s, h1 = ((bi + 1) * 64 + s - 1) / s;
  int w0 = (bj * 64) / s, w1 = ((bj + 1) * 64 + s - 1) / s;
  float inv = 1.f / (float)((h1 - h0) * (w1 - w0));
  __shared__ float vin[512];
  for (int i = threadIdx.x; i < Cin; i += 256)
    vin[i] = in[((size_t)n * Cin + i) * P + p] * inv;
  __syncthreads();
  for (int o = threadIdx.x; o < Cout; o += 256) {
    float acc = 0.f;
    const float* wr = w + (size_t)o * Cin;
    for (int c = 0; c < Cin; ++c) acc = fmaf(vin[c], wr[c], acc);
    out[((size_t)n * Cout + o) * P + p] = fmaxf(fmaf(acc, bnS[o], bnB[o]), 0.f);
  }
}

// ======================================================================
// PPM upsample fill: psp16[n][px][2048] f16 from popost (bilinear, once).
// grid (4096/16, B), block 256 = 16 px x 16 c-lanes.
// ======================================================================
__global__ void pspfill_k(const float* __restrict__ p1, const float* __restrict__ p2,
                          const float* __restrict__ p3, const float* __restrict__ p6,
                          _Float16* __restrict__ out) {
  int n = blockIdx.y;
  int pl = threadIdx.x >> 4;
  int cl = threadIdx.x & 15;
  int p = blockIdx.x * 16 + pl;
  int y = p >> 6, x = p & 63;
  const float* ppv[4] = {p1, p2, p3, p6};
  const int sv[4] = {1, 2, 3, 6};
  _Float16* op = out + ((size_t)n * 4096 + p) * 2048;
#pragma unroll
  for (int g = 0; g < 4; ++g) {
    int s = sv[g];
    float r = (float)(s - 1) / 63.0f;
    float ty = y * r, tx = x * r;
    int y0 = (int)ty, x0 = (int)tx;
    int y1 = min(y0 + 1, s - 1), x1 = min(x0 + 1, s - 1);
    float fy = ty - y0, fx = tx - x0;
    float w00 = (1.f - fy) * (1.f - fx), w01 = (1.f - fy) * fx;
    float w10 = fy * (1.f - fx), w11 = fy * fx;
    const float* pb = ppv[g] + (size_t)n * 512 * s * s;
    int ss = s * s;
    for (int jj = 0; jj < 32; ++jj) {
      int lc = jj * 16 + cl;
      const float* b = pb + (size_t)lc * ss;
      float vv = w00 * b[y0 * s + x0] + w01 * b[y0 * s + x1] +
                 w10 * b[y1 * s + x0] + w11 * b[y1 * s + x1];
      op[g * 512 + lc] = (_Float16)vv;
    }
  }
}

// ======================================================================
extern "C" void kernel_launch(void* const* d_in, const int* in_sizes, int n_in,
                              void* d_out, int out_size, void* d_ws, size_t ws_size,
                              hipStream_t stream) {
  (void)in_sizes; (void)n_in; (void)out_size; (void)ws_size;
  const float* c2 = (const float*)d_in[1];
  const float* c3 = (const float*)d_in[2];
  const float* c4 = (const float*)d_in[3];
  const float* w5 = (const float*)d_in[4];
  const float* s5 = (const float*)d_in[5];
  const float* b5 = (const float*)d_in[6];
  const float* r4w = (const float*)d_in[7];
  const float* r4s = (const float*)d_in[8];
  const float* r4b = (const float*)d_in[9];
  const float* r4w2 = (const float*)d_in[10];
  const float* r4s2 = (const float*)d_in[11];
  const float* r4b2 = (const float*)d_in[12];
  const float* r3w = (const float*)d_in[13];
  const float* r3s = (const float*)d_in[14];
  const float* r3b = (const float*)d_in[15];
  const float* r3w2 = (const float*)d_in[16];
  const float* r3s2 = (const float*)d_in[17];
  const float* r3b2 = (const float*)d_in[18];
  const float* pw[4] = {(const float*)d_in[19], (const float*)d_in[22],
                        (const float*)d_in[25], (const float*)d_in[28]};
  const float* ps[4] = {(const float*)d_in[20], (const float*)d_in[23],
                        (const float*)d_in[26], (const float*)d_in[29]};
  const float* pbv[4] = {(const float*)d_in[21], (const float*)d_in[24],
                         (const float*)d_in[27], (const float*)d_in[30]};
  const float* pcw = (const float*)d_in[31];
  const float* pcs = (const float*)d_in[32];
  const float* pcb = (const float*)d_in[33];
  const float* w6 = (const float*)d_in[34];
  const float* b6 = (const float*)d_in[35];
  float* outp = (float*)d_out;

  char* ws = (char*)d_ws;
  size_t off = 0;
  auto alloc = [&](size_t bytes) -> char* {
    char* p = ws + off;
    off += (bytes + 255) & ~(size_t)255;
    return p;
  };
  // persistent
  _Float16* wt16 = (_Float16*)alloc(23040ULL * 512 * 2);     // 23.6 MB
  // R1 union: phase-1 buffers, later reused as conv5 (fp32 [4][512][4096])
  char* R1 = alloc(37896192);
  _Float16* wt5_16 = (_Float16*)(R1 + 0);                     // 18,874,368
  _Float16* c416   = (_Float16*)(R1 + 18874368);              //  4,194,304
  float*    out5   = (float*)   (R1 + 23068672);              //  2,097,152
  float*    q4     = (float*)   (R1 + 25165824);              //  2,097,152
  float*    k4     = (float*)   (R1 + 27262976);              //  2,097,152
  float*    att4   = (float*)   (R1 + 29360128);              //    147,456
  float*    out4   = (float*)   (R1 + 29507584);              //  8,388,608
  float*    conv5  = (float*)   (R1 + 0);                     // 33,554,432 (after out4 dead)
  float* q3   = (float*)alloc((size_t)NB * 64 * 4096 * 4);
  float* k3   = (float*)alloc((size_t)NB * 64 * 4096 * 4);
  float* att3 = (float*)alloc((size_t)NB * 4096 * 9 * 4);
  _Float16* out3_16 = (_Float16*)alloc((size_t)NB * 4096 * 512 * 2);   // 16.8 MB
  _Float16* psp16   = (_Float16*)alloc((size_t)NB * 4096 * 2048 * 2);  // 67.1 MB
  float* popreA = (float*)alloc((size_t)NB * 512 * 50 * 4);
  float* popostA = (float*)alloc((size_t)NB * 512 * 50 * 4);
  _Float16* zbuf = (_Float16*)alloc(8192);
  const int ssv[4] = {1, 2, 3, 6};
  const int slicev[4] = {8, 4, 2, 1};
  float* popre[4]; float* popost[4];
  {
    size_t o2 = 0;
    for (int i = 0; i < 4; ++i) {
      popre[i] = popreA + o2; popost[i] = popostA + o2;
      o2 += (size_t)NB * 512 * ssv[i] * ssv[i];
    }
  }

  (void)hipMemsetAsync(zbuf, 0, 8192, stream);
  (void)hipMemsetAsync(popreA, 0, (size_t)NB * 512 * 50 * 4, stream);

  // weight prep + c4 channel-last
  wprep_k<<<dim3(10, 9, 512), 256, 0, stream>>>(pcw, wt16, 2560);
  wprep_k<<<dim3(8, 9, 512), 256, 0, stream>>>(w5, wt5_16, 2048);
  tonhwc_k<<<dim3(1, 8, NB), 256, 0, stream>>>(c4, c416, 2048, 256, 256);

  // 1) out5 = relu(bn(conv3x3(c4, w5)))  via MFMA implicit GEMM
  gemm_conv3x3<<<dim3(8, 4), 256, 0, stream>>>(
      wt5_16, c416, c416, zbuf, s5, b5, out5, 2048, 2048, 2048, 16, 16, 4, 8, 1);

  // 2) level-4 local_up -> out4 [B,512,32,32]
  conv1x1_tile<0><<<dim3(16, 2, NB), 256, 0, stream>>>(c3, r4w, r4s, r4b, q4, 1024, 128, 32, 32, 32, 32, 0);
  conv1x1_tile<1><<<dim3(16, 2, NB), 256, 0, stream>>>(c4, r4w2, r4s2, r4b2, k4, 2048, 128, 16, 16, 32, 32, 0);
  att_scores<<<dim3(4, NB), 256, 0, stream>>>(q4, k4, att4, 128, 32, 32);
  att_apply_rs<0><<<dim3(32, NB), 256, 0, stream>>>(att4, out5, out4, 512, 32, 32, 16, 16);

  // 3) level-3 local_up -> out3_16 (channel-last f16)
  conv1x1_tile<0><<<dim3(64, 1, NB), 256, 0, stream>>>(c2, r3w, r3s, r3b, q3, 512, 64, 64, 64, 64, 64, 0);
  conv1x1_tile<1><<<dim3(64, 1, NB), 256, 0, stream>>>(c3, r3w2, r3s2, r3b2, k3, 1024, 64, 32, 32, 64, 64, 0);
  att_scores<<<dim3(16, NB), 256, 0, stream>>>(q3, k3, att3, 64, 64, 64);
  att_apply_rs<1><<<dim3(64, NB), 256, 0, stream>>>(att3, out4, out3_16, 512, 64, 64, 32, 32);

  // 4) PPM: pool sums -> 1x1 conv (with area div) -> bilinear fill psp16
  for (int i = 0; i < 4; ++i)
    apool_cl_k<<<dim3(ssv[i] * ssv[i], NB, slicev[i]), 256, 0, stream>>>(out3_16, popre[i], ssv[i], slicev[i]);
  for (int i = 0; i < 4; ++i)
    conv1x1_small<<<dim3(ssv[i] * ssv[i], NB), 256, 0, stream>>>(
        popre[i], pw[i], ps[i], pbv[i], popost[i], 512, 512, ssv[i]);
  pspfill_k<<<dim3(256, NB), 256, 0, stream>>>(popost[0], popost[1], popost[2], popost[3], psp16);

  // 5) big conv3x3 over virtual concat -> conv5 (fp32 NCHW) via MFMA
  gemm_conv3x3<<<dim3(128, 4), 256, 0, stream>>>(
      wt16, out3_16, psp16, zbuf, pcs, pcb, conv5, 2560, 512, 2048, 64, 64, 6, 12, 1);

  // 6) classifier 1x1 -> d_out [B,19,64,64]
  conv1x1_tile<0><<<dim3(64, 1, NB), 256, 0, stream>>>(conv5, w6, nullptr, b6, outp, 512, 19, 64, 64, 64, 64, 0);
}

// Round 5
// 2303.214 us; speedup vs baseline: 4.9741x; 1.5116x over previous
//
#include <hip/hip_runtime.h>
#include <cstdint>

#define NB 4   // batch

typedef _Float16 f16x8 __attribute__((ext_vector_type(8)));
typedef _Float16 f16x4 __attribute__((ext_vector_type(4)));
typedef float f32x16_t __attribute__((ext_vector_type(16)));

__device__ __forceinline__ void gload_lds16(const void* g, void* l) {
  // 16B direct global->LDS. LDS dest = wave-uniform base + lane*16 (linear).
  __builtin_amdgcn_global_load_lds((const __attribute__((address_space(1))) void*)g,
                                   (__attribute__((address_space(3))) void*)l, 16, 0, 0);
}

// ======================================================================
// Weight prep for 3x3 convs: wt16[co][t*Cc + c] = (f16) w[co][c*9 + t]
// grid (Cc/256, 9, 512)
// ======================================================================
__global__ void wprep_k(const float* __restrict__ w, _Float16* __restrict__ wt, int Cc) {
  int c = blockIdx.x * 256 + threadIdx.x;
  int t = blockIdx.y, co = blockIdx.z;
  wt[((size_t)co * 9 + t) * Cc + c] = (_Float16)w[((size_t)co * Cc + c) * 9 + t];
}

// flat fp32 -> f16 cast (1x1 conv weights, already [co][cin] k-contiguous)
__global__ void castw_k(const float* __restrict__ w, _Float16* __restrict__ o, int n) {
  int i = blockIdx.x * 256 + threadIdx.x;
  if (i < n) o[i] = (_Float16)w[i];
}

// ======================================================================
// NCHW fp32 -> channel-last f16 transpose via 32x32 LDS tile.
// grid (P/32, C/32, n), block 256 (32 lanes x 8 rows)
// ======================================================================
__global__ void cvt_cl_k(const float* __restrict__ in, _Float16* __restrict__ out,
                         int C, int P) {
  __shared__ _Float16 t[32][33];
  int n = blockIdx.z;
  int p0 = blockIdx.x * 32, c0 = blockIdx.y * 32;
  int lx = threadIdx.x & 31, ly = threadIdx.x >> 5;
#pragma unroll
  for (int k = 0; k < 4; ++k) {
    int c = c0 + ly + k * 8;
    t[ly + k * 8][lx] = (_Float16)in[((size_t)n * C + c) * P + p0 + lx];
  }
  __syncthreads();
#pragma unroll
  for (int k = 0; k < 4; ++k) {
    int p = p0 + ly + k * 8;
    out[((size_t)n * P + p) * C + c0 + lx] = t[lx][ly + k * 8];
  }
}

// ======================================================================
// Implicit-GEMM conv3x3 (pad=1, dil=1) — verified staging from R4.
// Output: channel-last f16 [px][512] with bn+relu (epilogue-only change).
// ======================================================================
__global__ __launch_bounds__(256, 2) void gemm_conv3x3(
    const _Float16* __restrict__ wt,
    const _Float16* __restrict__ src0,
    const _Float16* __restrict__ src1,
    const _Float16* __restrict__ zbuf,
    const float* __restrict__ bnS, const float* __restrict__ bnB,
    _Float16* __restrict__ out16,
    int Cc, int C0, int s1, int H, int W, int logW, int logHW)
{
  const int Ktot = 9 * Cc;
  const int tid = threadIdx.x;
  const int l = tid & 63, w = tid >> 6;
  const int wm = w >> 1, wn = w & 1;
  const int p0 = blockIdx.x * 128, co0 = blockIdx.y * 128;
  __shared__ __align__(16) _Float16 sm[32 * 512];   // A: 0..15, B: 16..31 (1KB chunks)

  const int ckoff = (l >> 5) * 8;

  const _Float16* gA[4];
  {
    int co = co0 + w * 32 + (l & 31);
    const _Float16* base = wt + (size_t)co * Ktot + ckoff;
#pragma unroll
    for (int i = 0; i < 4; ++i) gA[i] = base + i * 16;
  }
  const int pxs = p0 + w * 32 + (l & 31);
  const int xs = pxs & (W - 1), ys = (pxs >> logW) & (H - 1), ns = pxs >> logHW;

  f32x16_t acc00, acc01, acc10, acc11;
#pragma unroll
  for (int r = 0; r < 16; ++r) { acc00[r] = 0.f; acc01[r] = 0.f; acc10[r] = 0.f; acc11[r] = 0.f; }

  const int steps = Cc >> 6;
  for (int t = 0; t < 9; ++t) {
    int gy = ys + (t / 3) - 1, gx = xs + (t % 3) - 1;   // dil=1
    bool ok = ((unsigned)gy < (unsigned)H) && ((unsigned)gx < (unsigned)W);
    size_t prow = ((size_t)ns << logHW) + (gy << logW) + gx;
    const _Float16* pb0 = ok ? src0 + prow * C0 + ckoff : zbuf + ckoff;
    const _Float16* pb1 = ok ? src1 + prow * s1 - C0 + ckoff : zbuf + ckoff;
    for (int s = 0; s < steps; ++s) {
      int cbase = s << 6;
      __syncthreads();
#pragma unroll
      for (int i = 0; i < 4; ++i) {
        gload_lds16(gA[i], &sm[(w * 4 + i) * 512]);
        gA[i] += 64;
      }
#pragma unroll
      for (int i = 0; i < 4; ++i) {
        int csel = cbase + i * 16;
        const _Float16* p = ((csel + ckoff) < C0 ? pb0 : pb1) + csel;
        gload_lds16(p, &sm[16 * 512 + (w * 4 + i) * 512]);
      }
      __syncthreads();
#pragma unroll
      for (int kf = 0; kf < 4; ++kf) {
        f16x8 a0 = *(const f16x8*)&sm[((wm * 2 + 0) * 4 + kf) * 512 + l * 8];
        f16x8 a1 = *(const f16x8*)&sm[((wm * 2 + 1) * 4 + kf) * 512 + l * 8];
        f16x8 b0 = *(const f16x8*)&sm[16 * 512 + ((wn * 2 + 0) * 4 + kf) * 512 + l * 8];
        f16x8 b1 = *(const f16x8*)&sm[16 * 512 + ((wn * 2 + 1) * 4 + kf) * 512 + l * 8];
        acc00 = __builtin_amdgcn_mfma_f32_32x32x16_f16(a0, b0, acc00, 0, 0, 0);
        acc01 = __builtin_amdgcn_mfma_f32_32x32x16_f16(a0, b1, acc01, 0, 0, 0);
        acc10 = __builtin_amdgcn_mfma_f32_32x32x16_f16(a1, b0, acc10, 0, 0, 0);
        acc11 = __builtin_amdgcn_mfma_f32_32x32x16_f16(a1, b1, acc11, 0, 0, 0);
      }
    }
  }

  // epilogue: channel-last f16, row = (r&3)+8*(r>>2)+4*(l>>5), col(l&31)=px
  {
    const int xlo = l & 31;
    const int hi4 = 4 * (l >> 5);
#define EPI(ACC, ML, NL)                                                    \
    {                                                                       \
      int px = p0 + wn * 64 + (NL) * 32 + xlo;                              \
      _Float16* orow = out16 + (size_t)px * 512;                            \
      _Pragma("unroll")                                                     \
      for (int g = 0; g < 4; ++g) {                                         \
        int cob = co0 + wm * 64 + (ML) * 32 + 8 * g + hi4;                  \
        f16x4 st;                                                           \
        _Pragma("unroll")                                                   \
        for (int e = 0; e < 4; ++e) {                                       \
          float vv = fmaf(ACC[g * 4 + e], bnS[cob + e], bnB[cob + e]);      \
          st[e] = (_Float16)fmaxf(vv, 0.f);                                 \
        }                                                                   \
        *(f16x4*)(orow + cob) = st;                                         \
      }                                                                     \
    }
    EPI(acc00, 0, 0) EPI(acc01, 0, 1) EPI(acc10, 1, 0) EPI(acc11, 1, 1)
#undef EPI
  }
}

// ======================================================================
// 1x1-conv GEMM, channel-last f16 in/out, bn (no relu).
// tile MT co x 64 px, BK=64, 4 waves (2x2). grid (N/64).
// ======================================================================
template <int MT>
__global__ __launch_bounds__(256) void gemm1x1_cl(
    const _Float16* __restrict__ wA,    // [MT][K]
    const _Float16* __restrict__ inB,   // [N][K]
    const float* __restrict__ bnS, const float* __restrict__ bnB,
    _Float16* __restrict__ out16,       // [N][MT]
    int K)
{
  const int tid = threadIdx.x;
  const int l = tid & 63, w = tid >> 6;
  const int wm = w >> 1, wn = w & 1;
  const int p0 = blockIdx.x * 64;
  constexpr int ACH = (MT / 32) * 4;
  constexpr int TCH = ACH + 8;
  __shared__ __align__(16) _Float16 sm[TCH * 512];
  const int ckoff = (l >> 5) * 8;
  const int l31 = l & 31;

  constexpr int NFRAG = MT / 64;       // 2 for MT=128, 1 for MT=64
  f32x16_t acc[NFRAG];
#pragma unroll
  for (int i = 0; i < NFRAG; ++i)
#pragma unroll
    for (int r = 0; r < 16; ++r) acc[i][r] = 0.f;

  for (int kb = 0; kb < K; kb += 64) {
    __syncthreads();
    for (int c = w; c < TCH; c += 4) {      // c wave-uniform
      const _Float16* src;
      if (c < ACH) {
        int mf = c >> 2, kf = c & 3;
        src = wA + (size_t)(mf * 32 + l31) * K + kb + kf * 16 + ckoff;
      } else {
        int cb = c - ACH, nf = cb >> 2, kf = cb & 3;
        src = inB + (size_t)(p0 + nf * 32 + l31) * K + kb + kf * 16 + ckoff;
      }
      gload_lds16(src, &sm[c * 512]);
    }
    __syncthreads();
#pragma unroll
    for (int kf = 0; kf < 4; ++kf) {
      f16x8 b = *(const f16x8*)&sm[(ACH + wn * 4 + kf) * 512 + l * 8];
#pragma unroll
      for (int i = 0; i < NFRAG; ++i) {
        int mf = wm * NFRAG + i;
        f16x8 a = *(const f16x8*)&sm[(mf * 4 + kf) * 512 + l * 8];
        acc[i] = __builtin_amdgcn_mfma_f32_32x32x16_f16(a, b, acc[i], 0, 0, 0);
      }
    }
  }
  int px = p0 + wn * 32 + l31;
  _Float16* orow = out16 + (size_t)px * MT;
  const int hi4 = 4 * (l >> 5);
#pragma unroll
  for (int i = 0; i < NFRAG; ++i) {
#pragma unroll
    for (int g = 0; g < 4; ++g) {
      int cob = (wm * NFRAG + i) * 32 + 8 * g + hi4;
      f16x4 st;
#pragma unroll
      for (int e = 0; e < 4; ++e)
        st[e] = (_Float16)fmaf(acc[i][g * 4 + e], bnS[cob + e], bnB[cob + e]);
      *(f16x4*)(orow + cob) = st;
    }
  }
}

// ======================================================================
// channel-last bilinear resize (align_corners). thread = one f16x8 chunk.
// grid ((Ho*Wo*C/8)/256, n)
// ======================================================================
__global__ void resize_cl_k(const _Float16* __restrict__ in, _Float16* __restrict__ out,
                            int logLC, int Hi, int Wi, int logWo, int Ho, int Wo) {
  int n = blockIdx.y;
  int idx = blockIdx.x * 256 + threadIdx.x;
  int p = idx >> logLC;
  int C = 8 << logLC;
  int c8 = (idx & ((1 << logLC) - 1)) * 8;
  int y = p >> logWo, x = p & (Wo - 1);
  float ry = (float)(Hi - 1) / (float)(Ho - 1);
  float rx = (float)(Wi - 1) / (float)(Wo - 1);
  float ty = y * ry, tx = x * rx;
  int y0 = (int)ty, x0 = (int)tx;
  int y1 = min(y0 + 1, Hi - 1), x1 = min(x0 + 1, Wi - 1);
  float fy = ty - y0, fx = tx - x0;
  const _Float16* b = in + (size_t)n * Hi * Wi * C + c8;
  f16x8 v00 = *(const f16x8*)(b + (size_t)(y0 * Wi + x0) * C);
  f16x8 v01 = *(const f16x8*)(b + (size_t)(y0 * Wi + x1) * C);
  f16x8 v10 = *(const f16x8*)(b + (size_t)(y1 * Wi + x0) * C);
  f16x8 v11 = *(const f16x8*)(b + (size_t)(y1 * Wi + x1) * C);
  f16x8 st;
#pragma unroll
  for (int e = 0; e < 8; ++e) {
    float a = (float)v00[e] * (1.f - fy) + (float)v10[e] * fy;
    float c = (float)v01[e] * (1.f - fy) + (float)v11[e] * fy;
    st[e] = (_Float16)(a * (1.f - fx) + c * fx);
  }
  *(f16x8*)(out + ((size_t)n * Ho * Wo + p) * C + c8) = st;
}

// ======================================================================
// FUSED local attention: scores (dil-2 3x3) + softmax + PV with bilinear
// resize of v. q,k: [Ntot][KD] ch-last f16 at HxW; v: [n][Hv*Wv][512].
// out: [Ntot][512] f16. Block 256 = 32 px x 8 splits. grid (Ntot/32).
// OOB taps: score stays 0 (participates in softmax), PV contribution 0.
// ======================================================================
template <int KD>
__global__ __launch_bounds__(256) void fused_att_k(
    const _Float16* __restrict__ q16, const _Float16* __restrict__ k16,
    const _Float16* __restrict__ v16, _Float16* __restrict__ out16,
    int logP, int logW, int H, int W, int Hv, int Wv)
{
  const int tid = threadIdx.x;
  const int pxl = tid >> 3, sp = tid & 7;
  const int pg = blockIdx.x * 32 + pxl;       // global flat px (incl n)
  const int n = pg >> logP;
  const int pl = pg & ((1 << logP) - 1);
  const int y = pl >> logW, x = pl & (W - 1);

  // ---- phase 1: scores (8-way k-split per px)
  constexpr int CPS = KD / 64;                // f16x8 chunks per split
  const _Float16* qrow = q16 + (size_t)pg * KD + sp * (CPS * 8);
  f16x8 qv[CPS];
#pragma unroll
  for (int i = 0; i < CPS; ++i) qv[i] = *(const f16x8*)(qrow + i * 8);
  float sc[9];
#pragma unroll
  for (int j = 0; j < 9; ++j) {
    int yy = y + (j / 3) * 2 - 2, xx = x + (j % 3) * 2 - 2;
    float s = 0.f;
    if ((unsigned)yy < (unsigned)H && (unsigned)xx < (unsigned)W) {
      const _Float16* krow = k16 + ((size_t)(n << logP) + yy * W + xx) * KD + sp * (CPS * 8);
#pragma unroll
      for (int i = 0; i < CPS; ++i) {
        f16x8 kv = *(const f16x8*)(krow + i * 8);
#pragma unroll
        for (int e = 0; e < 8; ++e) s = fmaf((float)qv[i][e], (float)kv[e], s);
      }
    }
    sc[j] = s;
  }
#pragma unroll
  for (int j = 0; j < 9; ++j) {
    float v = sc[j];
    v += __shfl_xor(v, 1); v += __shfl_xor(v, 2); v += __shfl_xor(v, 4);
    sc[j] = v;
  }
  float m = sc[0];
#pragma unroll
  for (int j = 1; j < 9; ++j) m = fmaxf(m, sc[j]);
  float a[9], ssum = 0.f;
#pragma unroll
  for (int j = 0; j < 9; ++j) { a[j] = expf(sc[j] - m); ssum += a[j]; }
  float inv = 1.f / ssum;
#pragma unroll
  for (int j = 0; j < 9; ++j) a[j] *= inv;

  // ---- phase 2: PV, thread handles 64 channels (sp*64..) for its px
  const float rh = (float)(Hv - 1) / (float)(H - 1);
  const float rw = (float)(Wv - 1) / (float)(W - 1);
  float acc[8][8];
#pragma unroll
  for (int v8 = 0; v8 < 8; ++v8)
#pragma unroll
    for (int e = 0; e < 8; ++e) acc[v8][e] = 0.f;
  const _Float16* vb = v16 + (size_t)n * Hv * Wv * 512 + sp * 64;
#pragma unroll
  for (int j = 0; j < 9; ++j) {
    int yy = y + (j / 3) * 2 - 2, xx = x + (j % 3) * 2 - 2;
    if ((unsigned)yy >= (unsigned)H || (unsigned)xx >= (unsigned)W) continue;
    float ty = yy * rh, tx = xx * rw;
    int y0 = (int)ty, x0 = (int)tx;
    int y1 = min(y0 + 1, Hv - 1), x1 = min(x0 + 1, Wv - 1);
    float fy = ty - y0, fx = tx - x0;
    const _Float16* r00 = vb + (size_t)(y0 * Wv + x0) * 512;
    const _Float16* r01 = vb + (size_t)(y0 * Wv + x1) * 512;
    const _Float16* r10 = vb + (size_t)(y1 * Wv + x0) * 512;
    const _Float16* r11 = vb + (size_t)(y1 * Wv + x1) * 512;
    float w00 = a[j] * (1.f - fy) * (1.f - fx), w01 = a[j] * (1.f - fy) * fx;
    float w10 = a[j] * fy * (1.f - fx),         w11 = a[j] * fy * fx;
#pragma unroll
    for (int v8 = 0; v8 < 8; ++v8) {
      f16x8 c00 = *(const f16x8*)(r00 + v8 * 8);
      f16x8 c01 = *(const f16x8*)(r01 + v8 * 8);
      f16x8 c10 = *(const f16x8*)(r10 + v8 * 8);
      f16x8 c11 = *(const f16x8*)(r11 + v8 * 8);
#pragma unroll
      for (int e = 0; e < 8; ++e)
        acc[v8][e] += w00 * (float)c00[e] + w01 * (float)c01[e] +
                      w10 * (float)c10[e] + w11 * (float)c11[e];
    }
  }
  _Float16* orow = out16 + (size_t)pg * 512 + sp * 64;
#pragma unroll
  for (int v8 = 0; v8 < 8; ++v8) {
    f16x8 st;
#pragma unroll
    for (int e = 0; e < 8; ++e) st[e] = (_Float16)acc[v8][e];
    *(f16x8*)(orow + v8 * 8) = st;
  }
}

// ======================================================================
// adaptive avg pool from channel-last f16 [n][4096][512] -> SUMS (atomic)
// ======================================================================
__global__ void apool_cl_k(const _Float16* __restrict__ in, float* __restrict__ out,
                           int s, int slices) {
  int bin = blockIdx.x, n = blockIdx.y, sl = blockIdx.z;
  int i = bin / s, j = bin - i * s;
  int h0 = (i * 64) / s, h1 = ((i + 1) * 64 + s - 1) / s;
  int w0 = (j * 64) / s, w1 = ((j + 1) * 64 + s - 1) / s;
  float a0 = 0.f, a1 = 0.f;
  for (int y = h0 + sl; y < h1; y += slices)
    for (int x = w0; x < w1; ++x) {
      const _Float16* r = in + ((size_t)n * 4096 + y * 64 + x) * 512;
      a0 += (float)r[threadIdx.x];
      a1 += (float)r[threadIdx.x + 256];
    }
  atomicAdd(&out[((size_t)n * 512 + threadIdx.x) * (s * s) + bin], a0);
  atomicAdd(&out[((size_t)n * 512 + threadIdx.x + 256) * (s * s) + bin], a1);
}

// ======================================================================
// tiny 1x1 conv for pooled SUMS (divides by bin area), bn+relu.
// ======================================================================
__global__ void conv1x1_small(const float* __restrict__ in, const float* __restrict__ w,
                              const float* __restrict__ bnS, const float* __restrict__ bnB,
                              float* __restrict__ out, int Cin, int Cout, int s) {
  int n = blockIdx.y, p = blockIdx.x;
  int P = s * s;
  int bi = p / s, bj = p - bi * s;
  int h0 = (bi * 64) / s, h1 = ((bi + 1) * 64 + s - 1) / s;
  int w0 = (bj * 64) / s, w1 = ((bj + 1) * 64 + s - 1) / s;
  float inv = 1.f / (float)((h1 - h0) * (w1 - w0));
  __shared__ float vin[512];
  for (int i = threadIdx.x; i < Cin; i += 256)
    vin[i] = in[((size_t)n * Cin + i) * P + p] * inv;
  __syncthreads();
  for (int o = threadIdx.x; o < Cout; o += 256) {
    float acc = 0.f;
    const float* wr = w + (size_t)o * Cin;
    for (int c = 0; c < Cin; ++c) acc = fmaf(vin[c], wr[c], acc);
    out[((size_t)n * Cout + o) * P + p] = fmaxf(fmaf(acc, bnS[o], bnB[o]), 0.f);
  }
}

// ======================================================================
// PPM upsample fill: psp16[n][px][2048] f16 from popost (bilinear, once).
// ======================================================================
__global__ void pspfill_k(const float* __restrict__ p1, const float* __restrict__ p2,
                          const float* __restrict__ p3, const float* __restrict__ p6,
                          _Float16* __restrict__ out) {
  int n = blockIdx.y;
  int pl = threadIdx.x >> 4;
  int cl = threadIdx.x & 15;
  int p = blockIdx.x * 16 + pl;
  int y = p >> 6, x = p & 63;
  const float* ppv[4] = {p1, p2, p3, p6};
  const int sv[4] = {1, 2, 3, 6};
  _Float16* op = out + ((size_t)n * 4096 + p) * 2048;
#pragma unroll
  for (int g = 0; g < 4; ++g) {
    int s = sv[g];
    float r = (float)(s - 1) / 63.0f;
    float ty = y * r, tx = x * r;
    int y0 = (int)ty, x0 = (int)tx;
    int y1 = min(y0 + 1, s - 1), x1 = min(x0 + 1, s - 1);
    float fy = ty - y0, fx = tx - x0;
    float w00 = (1.f - fy) * (1.f - fx), w01 = (1.f - fy) * fx;
    float w10 = fy * (1.f - fx), w11 = fy * fx;
    const float* pb = ppv[g] + (size_t)n * 512 * s * s;
    int ss = s * s;
    for (int jj = 0; jj < 32; ++jj) {
      int lc = jj * 16 + cl;
      const float* b = pb + (size_t)lc * ss;
      float vv = w00 * b[y0 * s + x0] + w01 * b[y0 * s + x1] +
                 w10 * b[y1 * s + x0] + w11 * b[y1 * s + x1];
      op[g * 512 + lc] = (_Float16)vv;
    }
  }
}

// ======================================================================
// classifier: conv5_16 [16384][512] ch-last f16 -> d_out fp32 [4][19][4096]
// block 256 = 64 px x 4 o-groups; w6 staged f16 in LDS. grid (16384/64)
// ======================================================================
__global__ __launch_bounds__(256) void classifier_k(
    const _Float16* __restrict__ conv5, const float* __restrict__ w6,
    const float* __restrict__ b6, float* __restrict__ outp) {
  __shared__ _Float16 wl[19 * 512];
  int tid = threadIdx.x;
  for (int i = tid; i < 19 * 512; i += 256) wl[i] = (_Float16)w6[i];
  __syncthreads();
  int pxl = tid & 63, og = tid >> 6;
  int p = blockIdx.x * 64 + pxl;
  const _Float16* row = conv5 + (size_t)p * 512;
  int o0 = og * 5;
  float acc[5] = {0.f, 0.f, 0.f, 0.f, 0.f};
  for (int ch = 0; ch < 64; ++ch) {
    f16x8 rv = *(const f16x8*)(row + ch * 8);
#pragma unroll
    for (int oo = 0; oo < 5; ++oo) {
      if (o0 + oo >= 19) break;
      f16x8 wv = *(const f16x8*)(&wl[(size_t)(o0 + oo) * 512 + ch * 8]);
#pragma unroll
      for (int e = 0; e < 8; ++e) acc[oo] = fmaf((float)rv[e], (float)wv[e], acc[oo]);
    }
  }
  int n = p >> 12, pp = p & 4095;
#pragma unroll
  for (int oo = 0; oo < 5; ++oo) {
    if (o0 + oo >= 19) break;
    outp[((size_t)n * 19 + o0 + oo) * 4096 + pp] = acc[oo] + b6[o0 + oo];
  }
}

// ======================================================================
extern "C" void kernel_launch(void* const* d_in, const int* in_sizes, int n_in,
                              void* d_out, int out_size, void* d_ws, size_t ws_size,
                              hipStream_t stream) {
  (void)in_sizes; (void)n_in; (void)out_size; (void)ws_size;
  const float* c2 = (const float*)d_in[1];
  const float* c3 = (const float*)d_in[2];
  const float* c4 = (const float*)d_in[3];
  const float* w5 = (const float*)d_in[4];
  const float* s5 = (const float*)d_in[5];
  const float* b5 = (const float*)d_in[6];
  const float* r4w = (const float*)d_in[7];
  const float* r4s = (const float*)d_in[8];
  const float* r4b = (const float*)d_in[9];
  const float* r4w2 = (const float*)d_in[10];
  const float* r4s2 = (const float*)d_in[11];
  const float* r4b2 = (const float*)d_in[12];
  const float* r3w = (const float*)d_in[13];
  const float* r3s = (const float*)d_in[14];
  const float* r3b = (const float*)d_in[15];
  const float* r3w2 = (const float*)d_in[16];
  const float* r3s2 = (const float*)d_in[17];
  const float* r3b2 = (const float*)d_in[18];
  const float* pw[4] = {(const float*)d_in[19], (const float*)d_in[22],
                        (const float*)d_in[25], (const float*)d_in[28]};
  const float* ps[4] = {(const float*)d_in[20], (const float*)d_in[23],
                        (const float*)d_in[26], (const float*)d_in[29]};
  const float* pbv[4] = {(const float*)d_in[21], (const float*)d_in[24],
                         (const float*)d_in[27], (const float*)d_in[30]};
  const float* pcw = (const float*)d_in[31];
  const float* pcs = (const float*)d_in[32];
  const float* pcb = (const float*)d_in[33];
  const float* w6 = (const float*)d_in[34];
  const float* b6 = (const float*)d_in[35];
  float* outp = (float*)d_out;

  char* ws = (char*)d_ws;
  size_t off = 0;
  auto alloc = [&](size_t bytes) -> char* {
    char* p = ws + off;
    off += (bytes + 255) & ~(size_t)255;
    return p;
  };
  _Float16* wt16   = (_Float16*)alloc(23040ULL * 512 * 2);        // 23.6 MB
  char*     SH     = alloc(18874368);                             // wt5_16 / conv5_16 union
  _Float16* wt5_16 = (_Float16*)SH;                               // used early
  _Float16* conv5_16 = (_Float16*)SH;                             // used late
  _Float16* c2_16  = (_Float16*)alloc((size_t)NB * 4096 * 512 * 2);
  _Float16* c3_16  = (_Float16*)alloc((size_t)NB * 1024 * 1024 * 2);
  _Float16* c4_16  = (_Float16*)alloc((size_t)NB * 256 * 2048 * 2);
  _Float16* r4w16  = (_Float16*)alloc(128 * 1024 * 2);
  _Float16* r4w216 = (_Float16*)alloc(128 * 2048 * 2);
  _Float16* r3w16  = (_Float16*)alloc(64 * 512 * 2);
  _Float16* r3w216 = (_Float16*)alloc(64 * 1024 * 2);
  _Float16* out5_16 = (_Float16*)alloc((size_t)NB * 256 * 512 * 2);
  _Float16* q4_16  = (_Float16*)alloc((size_t)NB * 1024 * 128 * 2);
  _Float16* k4s_16 = (_Float16*)alloc((size_t)NB * 256 * 128 * 2);
  _Float16* k4_16  = (_Float16*)alloc((size_t)NB * 1024 * 128 * 2);
  _Float16* out4_16 = (_Float16*)alloc((size_t)NB * 1024 * 512 * 2);
  _Float16* q3_16  = (_Float16*)alloc((size_t)NB * 4096 * 64 * 2);
  _Float16* k3s_16 = (_Float16*)alloc((size_t)NB * 1024 * 64 * 2);
  _Float16* k3_16  = (_Float16*)alloc((size_t)NB * 4096 * 64 * 2);
  _Float16* out3_16 = (_Float16*)alloc((size_t)NB * 4096 * 512 * 2);
  _Float16* psp16  = (_Float16*)alloc((size_t)NB * 4096 * 2048 * 2);  // 67.1 MB
  float* popreA  = (float*)alloc((size_t)NB * 512 * 50 * 4);
  float* popostA = (float*)alloc((size_t)NB * 512 * 50 * 4);
  _Float16* zbuf = (_Float16*)alloc(8192);
  const int ssv[4] = {1, 2, 3, 6};
  const int slicev[4] = {8, 4, 2, 1};
  float* popre[4]; float* popost[4];
  {
    size_t o2 = 0;
    for (int i = 0; i < 4; ++i) {
      popre[i] = popreA + o2; popost[i] = popostA + o2;
      o2 += (size_t)NB * 512 * ssv[i] * ssv[i];
    }
  }

  (void)hipMemsetAsync(zbuf, 0, 8192, stream);
  (void)hipMemsetAsync(popreA, 0, (size_t)NB * 512 * 50 * 4, stream);

  // --- prep: 3x3 weights, 1x1 weight casts, channel-last inputs
  wprep_k<<<dim3(10, 9, 512), 256, 0, stream>>>(pcw, wt16, 2560);
  wprep_k<<<dim3(8, 9, 512), 256, 0, stream>>>(w5, wt5_16, 2048);
  castw_k<<<512, 256, 0, stream>>>(r4w, r4w16, 128 * 1024);
  castw_k<<<1024, 256, 0, stream>>>(r4w2, r4w216, 128 * 2048);
  castw_k<<<128, 256, 0, stream>>>(r3w, r3w16, 64 * 512);
  castw_k<<<256, 256, 0, stream>>>(r3w2, r3w216, 64 * 1024);
  cvt_cl_k<<<dim3(128, 16, NB), 256, 0, stream>>>(c2, c2_16, 512, 4096);
  cvt_cl_k<<<dim3(32, 32, NB), 256, 0, stream>>>(c3, c3_16, 1024, 1024);
  cvt_cl_k<<<dim3(8, 64, NB), 256, 0, stream>>>(c4, c4_16, 2048, 256);

  // 1) out5 = relu(bn(conv3x3(c4, w5)))  [ch-last f16, 16x16]
  gemm_conv3x3<<<dim3(8, 4), 256, 0, stream>>>(
      wt5_16, c4_16, c4_16, zbuf, s5, b5, out5_16, 2048, 2048, 2048, 16, 16, 4, 8);

  // 2) level-4: q4 (32x32), k4 = resize(conv(c4)) [linearity], fused att
  gemm1x1_cl<128><<<64, 256, 0, stream>>>(r4w16, c3_16, r4s, r4b, q4_16, 1024);
  gemm1x1_cl<128><<<16, 256, 0, stream>>>(r4w216, c4_16, r4s2, r4b2, k4s_16, 2048);
  resize_cl_k<<<dim3(64, NB), 256, 0, stream>>>(k4s_16, k4_16, 4, 16, 16, 5, 32, 32);
  fused_att_k<128><<<128, 256, 0, stream>>>(q4_16, k4_16, out5_16, out4_16,
                                            10, 5, 32, 32, 16, 16);

  // 3) level-3: q3 (64x64), k3 = resize(conv(c3)), fused att -> out3_16
  gemm1x1_cl<64><<<256, 256, 0, stream>>>(r3w16, c2_16, r3s, r3b, q3_16, 512);
  gemm1x1_cl<64><<<64, 256, 0, stream>>>(r3w216, c3_16, r3s2, r3b2, k3s_16, 1024);
  resize_cl_k<<<dim3(128, NB), 256, 0, stream>>>(k3s_16, k3_16, 3, 32, 32, 6, 64, 64);
  fused_att_k<64><<<512, 256, 0, stream>>>(q3_16, k3_16, out4_16, out3_16,
                                           12, 6, 64, 64, 32, 32);

  // 4) PPM: pool sums -> 1x1 conv (area div) -> bilinear fill psp16
  for (int i = 0; i < 4; ++i)
    apool_cl_k<<<dim3(ssv[i] * ssv[i], NB, slicev[i]), 256, 0, stream>>>(
        out3_16, popre[i], ssv[i], slicev[i]);
  for (int i = 0; i < 4; ++i)
    conv1x1_small<<<dim3(ssv[i] * ssv[i], NB), 256, 0, stream>>>(
        popre[i], pw[i], ps[i], pbv[i], popost[i], 512, 512, ssv[i]);
  pspfill_k<<<dim3(256, NB), 256, 0, stream>>>(popost[0], popost[1], popost[2], popost[3], psp16);

  // 5) big conv3x3 over virtual concat -> conv5_16 (ch-last f16)
  gemm_conv3x3<<<dim3(128, 4), 256, 0, stream>>>(
      wt16, out3_16, psp16, zbuf, pcs, pcb, conv5_16, 2560, 512, 2048, 64, 64, 6, 12);

  // 6) classifier -> d_out [4,19,64,64] fp32
  classifier_k<<<256, 256, 0, stream>>>(conv5_16, w6, b6, outp);
}